// Round 15
// baseline (191.107 us; speedup 1.0000x reference)
//
#include <hip/hip_runtime.h>

#define NPG 116          // nodes per graph
#define EPG (NPG * 32)   // 3712 edges per graph
#define HID 32
#define HID2 64
#define EPS 1e-5f

#define AS 136           // bf16 tile k-stride (shorts) for W1T/L1T/L2T
#define YSS 40           // ysb/W2T k-stride (shorts)
#define HPG 7424         // per-graph 4B slots in buf: Wb (116x64 ints) -> h2 fp32

using bf16x8 = __attribute__((ext_vector_type(8))) short;
using f32x4  = __attribute__((ext_vector_type(4))) float;

__device__ __forceinline__ unsigned short f2bf(float f) {
  union { float f; unsigned int i; } cv;
  cv.f = f;
  unsigned int x = cv.i;
  x += 0x7fff + ((x >> 16) & 1);   // RNE
  return (unsigned short)(x >> 16);
}

#define MFMA16(a, b, c) __builtin_amdgcn_mfma_f32_16x16x32_bf16((a), (b), (c), 0, 0, 0)

// async global->LDS DMA, 16B per lane, 1 KB per wave-call.
// l must be wave-uniform; g is per-lane.
__device__ __forceinline__ void dma16(const void* g, void* l) {
  __builtin_amdgcn_global_load_lds(
      (const __attribute__((address_space(1))) void*)g,
      (__attribute__((address_space(3))) void*)l, 16, 0, 0);
}

// ---------------------------------------------------------------------------
// ws layout (floats) -- 97N + 32G + 256 = 46.2 MB (proven):
//   [0,256)   stats; [256,+N) dinv; [+32N) h1;
//   [+64N)    buf: Wb bf16 116x[64 ints] per graph -> overwritten by h2 fp32
//   [+32G)    z
// ---------------------------------------------------------------------------

// k_build: DMA edge triple into LDS -> W/deg LDS atomics -> pack Wb bf16.
// 1024 thr, ~99 KB LDS (1 block/CU); bulk DMA gives full-BW edge streaming.
__global__ __launch_bounds__(1024) void k_build(const int* __restrict__ ei,
                                                const float* __restrict__ ew,
                                                float* __restrict__ dinvg,
                                                float* __restrict__ buf,
                                                int N, int E) {
  __shared__ float Wf[NPG * NPG];   // 53824 B
  __shared__ int   eS[EPG];         // 14848 B
  __shared__ int   eD[EPG];         // 14848 B
  __shared__ float eW[EPG];         // 14848 B
  __shared__ float degs[NPG];
  const int g = blockIdx.x, tid = threadIdx.x;
  const int nb = g * NPG, e0 = g * EPG;
  const int w = tid >> 6, lane = tid & 63;

  // DMA: 3 arrays x 14 full 1KB calls (14336B each), tails by scalar copy
  for (int c = w; c < 42; c += 16) {
    int a = c / 14, k = c - a * 14;
    const int* gp;
    int* lp;
    if (a == 0)      { gp = ei + e0;             lp = eS; }
    else if (a == 1) { gp = ei + E + e0;         lp = eD; }
    else             { gp = (const int*)(ew + e0); lp = (int*)eW; }
    dma16(gp + k * 256 + lane * 4, lp + k * 256);
  }
  if (tid < 384) {
    int a = tid >> 7, i = (tid & 127) + 3584;
    if (a == 0)      eS[i] = ei[e0 + i];
    else if (a == 1) eD[i] = ei[E + e0 + i];
    else             ((int*)eW)[i] = ((const int*)(ew + e0))[i];
  }
  for (int i = tid; i < NPG; i += 1024) degs[i] = 1.0f;   // self-loop weight
  { float4* p = (float4*)Wf;
    for (int i = tid; i < NPG * 29; i += 1024) p[i] = make_float4(0,0,0,0); }
  __syncthreads();   // DMA drained

  for (int i = tid; i < EPG; i += 1024) {
    int s = eS[i] - nb, d = eD[i] - nb;
    float wv = eW[i];
    atomicAdd(&degs[d], wv);
    atomicAdd(&Wf[d * NPG + s], wv);
  }
  if (tid < NPG) atomicAdd(&Wf[tid * (NPG + 1)], 1.0f);
  __syncthreads();

  if (tid < NPG) dinvg[nb + tid] = rsqrtf(degs[tid]);
  int4* wb4 = (int4*)(buf + (size_t)g * HPG);   // 116*16 int4, rows 128 shorts
  for (int idx = tid; idx < NPG * 16; idx += 1024) {
    int r = idx >> 4, j8 = (idx & 15) * 8;
    float4 va = {0.f,0.f,0.f,0.f}, vb = {0.f,0.f,0.f,0.f};
    if (j8 < 112) {
      va = *(const float4*)&Wf[r * NPG + j8];
      vb = *(const float4*)&Wf[r * NPG + j8 + 4];
    } else if (j8 == 112) {
      va = *(const float4*)&Wf[r * NPG + 112];
    }
    int4 val;
    val.x = (unsigned)f2bf(va.x) | ((unsigned)f2bf(va.y) << 16);
    val.y = (unsigned)f2bf(va.z) | ((unsigned)f2bf(va.w) << 16);
    val.z = (unsigned)f2bf(vb.x) | ((unsigned)f2bf(vb.y) << 16);
    val.w = (unsigned)f2bf(vb.z) | ((unsigned)f2bf(vb.w) << 16);
    wb4[idx] = val;
  }
}

// k_conv1: DMA x-tile -> gemm1 MFMA -> L1T=bf16(dinv*lin1) -> h1=dinv*(Wb@L1')
// 1024 thr, ~72 KB LDS (2 blocks/CU).  Wb a-frags per-lane global prefetch.
__global__ __launch_bounds__(1024) void k_conv1(const float* __restrict__ x,
                                                const float* __restrict__ W1,
                                                const float* __restrict__ dinvg,
                                                const float* __restrict__ buf,
                                                float* __restrict__ h1,
                                                float* __restrict__ stats,
                                                int N) {
  __shared__ __align__(16) float xs[NPG * NPG];   // 53824 B
  __shared__ __align__(16) short W1T[HID * AS];   // 8704 B
  __shared__ __align__(16) short L1T[HID * AS];   // 8704 B
  __shared__ float dv[NPG];
  __shared__ float ss[HID], qs[HID];
  const int g = blockIdx.x, tid = threadIdx.x;
  const int nb = g * NPG;
  const int w = tid >> 6, lane = tid & 63;
  const int rf = lane & 15, kg = lane >> 4;
  const int mt = w >> 1, nt = w & 1, rl = mt * 16 + rf;   // 16 waves, 16 tiles

  // DMA x tile: 52 full 1KB calls + 144-float tail
  const float* xg = x + (size_t)nb * NPG;
  for (int c = w; c < 52; c += 16)
    dma16(xg + c * 256 + lane * 4, xs + c * 256);
  if (tid < 144) xs[13312 + tid] = xg[13312 + tid];

  // Wb a-frag prefetch (per-lane 4x16B; may sink -- one extra round at worst)
  bf16x8 av[4];
  {
    const unsigned short* wbs = (const unsigned short*)(buf + (size_t)g * HPG);
    const int rs = (rl < NPG ? rl : 0) * 128;
#pragma unroll
    for (int kk = 0; kk < 4; ++kk)
      av[kk] = *(const bf16x8*)&wbs[rs + kk * 32 + kg * 8];
  }
  if (tid < HID) { ss[tid] = 0.0f; qs[tid] = 0.0f; }
  for (int i = tid; i < NPG; i += 1024) dv[i] = dinvg[nb + i];
  for (int i = tid; i < HID * 20; i += 1024) {   // k-pad cols 116..135
    int c = i / 20, k = 116 + (i - 20 * (i / 20));
    W1T[c * AS + k] = 0;
    L1T[c * AS + k] = 0;
  }
  for (int i = tid; i < NPG * 8; i += 1024) {    // W1T[c][k] = W1[k][c]
    int k = i >> 3, c4 = (i & 7) * 4;
    float4 v = ((const float4*)W1)[i];
    W1T[(c4 + 0) * AS + k] = (short)f2bf(v.x);
    W1T[(c4 + 1) * AS + k] = (short)f2bf(v.y);
    W1T[(c4 + 2) * AS + k] = (short)f2bf(v.z);
    W1T[(c4 + 3) * AS + k] = (short)f2bf(v.w);
  }
  __syncthreads();   // x DMA + staging complete

  // P1: gemm1 -> L1T (scaled by dinv)
  {
    f32x4 a0 = {0.f,0.f,0.f,0.f}, a1 = {0.f,0.f,0.f,0.f};
#pragma unroll
    for (int kk = 0; kk < 4; ++kk) {
      const int off = kk * 32 + kg * 8;
      bf16x8 a;
      if (rl < NPG) {
        const float* xr = xs + rl * NPG;
        float4 v0 = {0.f,0.f,0.f,0.f}, v1 = {0.f,0.f,0.f,0.f};
        if (off + 8 <= NPG) {
          v0 = *(const float4*)(xr + off);
          v1 = *(const float4*)(xr + off + 4);
        } else if (off + 4 <= NPG) {
          v0 = *(const float4*)(xr + off);
        }
        a[0] = (short)f2bf(v0.x); a[1] = (short)f2bf(v0.y);
        a[2] = (short)f2bf(v0.z); a[3] = (short)f2bf(v0.w);
        a[4] = (short)f2bf(v1.x); a[5] = (short)f2bf(v1.y);
        a[6] = (short)f2bf(v1.z); a[7] = (short)f2bf(v1.w);
      } else {
#pragma unroll
        for (int j = 0; j < 8; ++j) a[j] = 0;
      }
      bf16x8 b0 = *(const bf16x8*)&W1T[rf * AS + off];
      bf16x8 b1 = *(const bf16x8*)&W1T[(16 + rf) * AS + off];
      a0 = MFMA16(a, b0, a0);
      a1 = MFMA16(a, b1, a1);
    }
#pragma unroll
    for (int i = 0; i < 4; ++i) {
      int row = mt * 16 + kg * 4 + i;
      if (row < NPG) {
        float dr = dv[row];
        L1T[rf * AS + row] = (short)f2bf(dr * a0[i]);
        L1T[(16 + rf) * AS + row] = (short)f2bf(dr * a1[i]);
      }
    }
  }
  __syncthreads();   // L1T ready

  // P2: h1 = dv*(Wb @ L1')
  {
    const bool ok = rl < NPG;
    f32x4 a0 = {0.f,0.f,0.f,0.f}, a1 = {0.f,0.f,0.f,0.f};
#pragma unroll
    for (int kk = 0; kk < 4; ++kk) {
      bf16x8 a = av[kk];
      if (!ok) {
#pragma unroll
        for (int j = 0; j < 8; ++j) a[j] = 0;
      }
      bf16x8 b0 = *(const bf16x8*)&L1T[rf * AS + kk * 32 + kg * 8];
      bf16x8 b1 = *(const bf16x8*)&L1T[(16 + rf) * AS + kk * 32 + kg * 8];
      a0 = MFMA16(a, b0, a0);
      a1 = MFMA16(a, b1, a1);
    }
    float s0 = 0.f, q0 = 0.f, s1 = 0.f, q1 = 0.f;
#pragma unroll
    for (int i = 0; i < 4; ++i) {
      int row = mt * 16 + kg * 4 + i;
      if (row < NPG) {
        float dr = dv[row];
        float v0 = dr * a0[i], v1 = dr * a1[i];
        float* hrow = h1 + (size_t)(nb + row) * HID;
        hrow[rf] = v0;
        hrow[16 + rf] = v1;
        s0 += v0; q0 += v0 * v0;
        s1 += v1; q1 += v1 * v1;
      }
    }
    atomicAdd(&ss[rf], s0);      atomicAdd(&qs[rf], q0);
    atomicAdd(&ss[16 + rf], s1); atomicAdd(&qs[16 + rf], q1);
  }
  __syncthreads();
  if (tid < HID) {
    atomicAdd(&stats[tid], ss[tid]);
    atomicAdd(&stats[32 + tid], qs[tid]);
  }
}

// k_conv2: DMA Wb->Ab (linear) + h1->h1s -> ys bf16 -> gemm2 -> h2=dv*(W@L2')
// 1024 thr, ~78.5 KB LDS (2 blocks/CU).
__global__ __launch_bounds__(1024) void k_conv2(const float* __restrict__ h1,
                                                const float* __restrict__ W2,
                                                const float* __restrict__ g1,
                                                const float* __restrict__ be1,
                                                const float* __restrict__ stats,
                                                const float* __restrict__ dinvg,
                                                float* __restrict__ buf,
                                                float* __restrict__ stats2,
                                                float invN, int N) {
  __shared__ __align__(16) short Ab[NPG * 128];    // 29696 B (linear rows)
  __shared__ __align__(16) float h1s[NPG * HID];   // 14848 B
  __shared__ __align__(16) short ysb[128 * YSS];   // 10240 B
  __shared__ __align__(16) short W2T[HID2 * YSS];  // 5120 B
  __shared__ __align__(16) short L2T[HID2 * AS];   // 17408 B
  __shared__ float dv[NPG];
  __shared__ float ss[HID2], qs[HID2];
  __shared__ float a1s[HID], c1s[HID];
  const int g = blockIdx.x, tid = threadIdx.x;
  const int nb = g * NPG;
  const int w = tid >> 6, lane = tid & 63;
  const int rf = lane & 15, kg = lane >> 4;
  float* bufg = buf + (size_t)g * HPG;

  // DMA: Ab = 29 full calls (29696B exactly); h1s = 14 calls + 128-float tail
  const short* wbg = (const short*)bufg;
  const float* h1g = h1 + (size_t)nb * HID;
  for (int c = w; c < 43; c += 16) {
    if (c < 29) dma16(wbg + c * 512 + lane * 8, (short*)Ab + c * 512);
    else {
      int k = c - 29;
      dma16(h1g + k * 256 + lane * 4, h1s + k * 256);
    }
  }
  if (tid < 128) h1s[3584 + tid] = h1g[3584 + tid];

  if (tid < HID) {
    float m = stats[tid] * invN;
    float v = stats[32 + tid] * invN - m * m;
    float a = g1[tid] * rsqrtf(v + EPS);
    a1s[tid] = a;
    c1s[tid] = be1[tid] - m * a;
  }
  if (tid < HID2) { ss[tid] = 0.0f; qs[tid] = 0.0f; }
  { int* p = (int*)ysb;
    for (int i = tid; i < 128 * YSS / 2; i += 1024) p[i] = 0; }
  { int* p = (int*)L2T;
    for (int i = tid; i < HID2 * AS / 2; i += 1024) p[i] = 0; }
  if (tid < 512) {   // W2T[c][k] = W2[k][c], one float4 each
    int k = tid >> 4, c4 = (tid & 15) * 4;
    float4 v = ((const float4*)W2)[tid];
    W2T[(c4 + 0) * YSS + k] = (short)f2bf(v.x);
    W2T[(c4 + 1) * YSS + k] = (short)f2bf(v.y);
    W2T[(c4 + 2) * YSS + k] = (short)f2bf(v.z);
    W2T[(c4 + 3) * YSS + k] = (short)f2bf(v.w);
  }
  for (int i = tid; i < NPG; i += 1024) dv[i] = dinvg[nb + i];
  __syncthreads();   // DMA drained, staging done

  // P1: ysb = bf16(dv[r]*relu(a1*h1+c1)) from LDS h1s
  if (tid < NPG * 8) {
    float4 hv = ((const float4*)h1s)[tid];
    int r = tid >> 3, kc = tid & 7, k0 = kc * 4;
    float dr = dv[r];
    float y0 = dr * fmaxf(0.f, a1s[k0 + 0] * hv.x + c1s[k0 + 0]);
    float y1 = dr * fmaxf(0.f, a1s[k0 + 1] * hv.y + c1s[k0 + 1]);
    float y2 = dr * fmaxf(0.f, a1s[k0 + 2] * hv.z + c1s[k0 + 2]);
    float y3 = dr * fmaxf(0.f, a1s[k0 + 3] * hv.w + c1s[k0 + 3]);
    unsigned int* yp = (unsigned int*)&ysb[r * YSS + k0];
    yp[0] = (unsigned)f2bf(y0) | ((unsigned)f2bf(y1) << 16);
    yp[1] = (unsigned)f2bf(y2) | ((unsigned)f2bf(y3) << 16);
  }
  __syncthreads();

  // P2: gemm2: L2T = ys'@W2 (32 tiles / 16 waves = 2 per wave; K=32)
#pragma unroll
  for (int u = 0; u < 2; ++u) {
    const int t = w + 16 * u;
    const int mt2 = t >> 2, ntc = t & 3;
    bf16x8 a = *(const bf16x8*)&ysb[(mt2 * 16 + rf) * YSS + kg * 8];
    bf16x8 b = *(const bf16x8*)&W2T[(ntc * 16 + rf) * YSS + kg * 8];
    f32x4 acc = {0.f, 0.f, 0.f, 0.f};
    acc = MFMA16(a, b, acc);
    const int col = ntc * 16 + rf;
#pragma unroll
    for (int i = 0; i < 4; ++i) {
      int row = mt2 * 16 + kg * 4 + i;
      if (row < NPG) L2T[col * AS + row] = (short)f2bf(acc[i]);
    }
  }
  __syncthreads();   // L2T ready

  // P3: h2 = dv*(W @ L2'): wave -> mt = w&7, 2 n-tiles (w>>3)
  {
    const int mt = w & 7, ntp = (w >> 3) * 2;
    const int rl = mt * 16 + rf;
    const bool ok = rl < NPG;
    f32x4 acc[2] = {{0.f,0.f,0.f,0.f},{0.f,0.f,0.f,0.f}};
#pragma unroll
    for (int kk = 0; kk < 4; ++kk) {
      bf16x8 a;
      if (ok) a = *(const bf16x8*)&Ab[(rl < NPG ? rl : 0) * 128 + kk * 32 + kg * 8];
      else {
#pragma unroll
        for (int j = 0; j < 8; ++j) a[j] = 0;
      }
#pragma unroll
      for (int u = 0; u < 2; ++u) {
        bf16x8 b = *(const bf16x8*)&L2T[((ntp + u) * 16 + rf) * AS + kk * 32 + kg * 8];
        acc[u] = MFMA16(a, b, acc[u]);
      }
    }
#pragma unroll
    for (int u = 0; u < 2; ++u) {
      const int col = (ntp + u) * 16 + rf;
      float s_ = 0.f, q_ = 0.f;
#pragma unroll
      for (int i = 0; i < 4; ++i) {
        int row = mt * 16 + kg * 4 + i;
        if (row < NPG) {
          float v = dv[row] * acc[u][i];
          bufg[row * HID2 + col] = v;     // h2 overlays Wb (Ab copy in LDS)
          s_ += v; q_ += v * v;
        }
      }
      atomicAdd(&ss[col], s_);
      atomicAdd(&qs[col], q_);
    }
  }
  __syncthreads();
  if (tid < HID2) {
    atomicAdd(&stats2[tid], ss[tid]);
    atomicAdd(&stats2[64 + tid], qs[tid]);
  }
}

// per-graph BN2 coefs + relu, mean/max pool, FC1 -> z
__global__ __launch_bounds__(256) void k_pool(const float* __restrict__ buf,
                                              const float* __restrict__ g2,
                                              const float* __restrict__ be2,
                                              const float* __restrict__ stats2,
                                              const float* __restrict__ Wf1,
                                              float* __restrict__ z,
                                              float invN, int N) {
  __shared__ float4 psum4[256], pmax4[256];
  __shared__ __align__(16) float emb[128];
  __shared__ __align__(16) float a2s[HID2], c2s[HID2];
  int g = blockIdx.x, tid = threadIdx.x;
  if (tid < HID2) {
    float m = stats2[tid] * invN;
    float v = stats2[64 + tid] * invN - m * m;
    float a = g2[tid] * rsqrtf(v + EPS);
    a2s[tid] = a;
    c2s[tid] = be2[tid] - m * a;
  }
  __syncthreads();
  int c4 = tid & 15, rg = tid >> 4;
  float4 av = ((const float4*)a2s)[c4], bv = ((const float4*)c2s)[c4];
  const float4* h4 = (const float4*)(buf + (size_t)g * HPG);
  float4 s = {0.f, 0.f, 0.f, 0.f};
  float4 mx = {-1e30f, -1e30f, -1e30f, -1e30f};
  for (int n = rg; n < NPG; n += 16) {
    float4 v = h4[n * 16 + c4];
    float4 y;
    y.x = fmaxf(0.f, av.x * v.x + bv.x);
    y.y = fmaxf(0.f, av.y * v.y + bv.y);
    y.z = fmaxf(0.f, av.z * v.z + bv.z);
    y.w = fmaxf(0.f, av.w * v.w + bv.w);
    s.x += y.x; s.y += y.y; s.z += y.z; s.w += y.w;
    mx.x = fmaxf(mx.x, y.x); mx.y = fmaxf(mx.y, y.y);
    mx.z = fmaxf(mx.z, y.z); mx.w = fmaxf(mx.w, y.w);
  }
  psum4[rg * 16 + c4] = s;
  pmax4[rg * 16 + c4] = mx;
  __syncthreads();
  if (tid < 16) {
    float4 S = psum4[tid], M = pmax4[tid];
    for (int j = 1; j < 16; ++j) {
      float4 p = psum4[j * 16 + tid], q = pmax4[j * 16 + tid];
      S.x += p.x; S.y += p.y; S.z += p.z; S.w += p.w;
      M.x = fmaxf(M.x, q.x); M.y = fmaxf(M.y, q.y);
      M.z = fmaxf(M.z, q.z); M.w = fmaxf(M.w, q.w);
    }
    const float inv = 1.0f / NPG;
    ((float4*)emb)[tid] = make_float4(S.x * inv, S.y * inv, S.z * inv, S.w * inv);
    ((float4*)emb)[16 + tid] = M;
  }
  __syncthreads();
  if (tid < 32) {
    float acc = 0.0f;
#pragma unroll
    for (int k = 0; k < 128; ++k) acc += emb[k] * Wf1[k * 32 + tid];
    z[g * 32 + tid] = acc;
  }
}

// single block (1024 thr): BNf stats over z -> coeffs -> relu -> FC2 -> out
__global__ __launch_bounds__(1024) void k_final(const float* __restrict__ z,
                                                const float* __restrict__ gf,
                                                const float* __restrict__ bef,
                                                const float* __restrict__ Wf2,
                                                const float* __restrict__ bf2,
                                                float* __restrict__ out, int G) {
  __shared__ float ss[32], qs[32], af[32], cf[32];
  __shared__ float w2s[64], b2s[2];
  int tid = threadIdx.x;
  const float4* z4 = (const float4*)z;
  int n4 = G * 8;   // 8192
  if (tid < 32) { ss[tid] = 0.0f; qs[tid] = 0.0f; }
  if (tid < 64) w2s[tid] = Wf2[tid];
  if (tid < 2) b2s[tid] = bf2[tid];
  __syncthreads();
  float4 s = {0.f, 0.f, 0.f, 0.f}, q = {0.f, 0.f, 0.f, 0.f};
  for (int i = tid; i < n4; i += 1024) {
    float4 v = z4[i];
    s.x += v.x; s.y += v.y; s.z += v.z; s.w += v.w;
    q.x += v.x * v.x; q.y += v.y * v.y; q.z += v.z * v.z; q.w += v.w * v.w;
  }
  int cg = (tid & 7) * 4;
  atomicAdd(&ss[cg + 0], s.x); atomicAdd(&ss[cg + 1], s.y);
  atomicAdd(&ss[cg + 2], s.z); atomicAdd(&ss[cg + 3], s.w);
  atomicAdd(&qs[cg + 0], q.x); atomicAdd(&qs[cg + 1], q.y);
  atomicAdd(&qs[cg + 2], q.z); atomicAdd(&qs[cg + 3], q.w);
  __syncthreads();
  if (tid < 32) {
    float invG = 1.0f / G;
    float m = ss[tid] * invG;
    float v = qs[tid] * invG - m * m;
    float a = gf[tid] * rsqrtf(v + EPS);
    af[tid] = a;
    cf[tid] = bef[tid] - m * a;
  }
  __syncthreads();
  for (int g = tid; g < G; g += 1024) {
    float o0 = b2s[0], o1 = b2s[1];
    const float4* zr = z4 + g * 8;
#pragma unroll
    for (int kc = 0; kc < 8; ++kc) {
      float4 v = zr[kc];
      int j = 4 * kc;
      float y;
      y = fmaxf(0.f, af[j + 0] * v.x + cf[j + 0]);
      o0 += y * w2s[2 * (j + 0)]; o1 += y * w2s[2 * (j + 0) + 1];
      y = fmaxf(0.f, af[j + 1] * v.y + cf[j + 1]);
      o0 += y * w2s[2 * (j + 1)]; o1 += y * w2s[2 * (j + 1) + 1];
      y = fmaxf(0.f, af[j + 2] * v.z + cf[j + 2]);
      o0 += y * w2s[2 * (j + 2)]; o1 += y * w2s[2 * (j + 2) + 1];
      y = fmaxf(0.f, af[j + 3] * v.w + cf[j + 3]);
      o0 += y * w2s[2 * (j + 3)]; o1 += y * w2s[2 * (j + 3) + 1];
    }
    out[g * 2] = o0;
    out[g * 2 + 1] = o1;
  }
}

extern "C" void kernel_launch(void* const* d_in, const int* in_sizes, int n_in,
                              void* d_out, int out_size, void* d_ws, size_t ws_size,
                              hipStream_t stream) {
  const float* x   = (const float*)d_in[0];
  const int*   ei  = (const int*)d_in[1];
  const float* ew  = (const float*)d_in[2];
  // d_in[3]=batch (implicit), d_in[5]=b1, d_in[9]=b2, d_in[13]=bf1 cancel
  // under training-mode BN and are unused.
  const float* W1  = (const float*)d_in[4];
  const float* g1  = (const float*)d_in[6];
  const float* be1 = (const float*)d_in[7];
  const float* W2  = (const float*)d_in[8];
  const float* g2  = (const float*)d_in[10];
  const float* be2 = (const float*)d_in[11];
  const float* Wf1 = (const float*)d_in[12];
  const float* gf  = (const float*)d_in[14];
  const float* bef = (const float*)d_in[15];
  const float* Wf2 = (const float*)d_in[16];
  const float* bf2 = (const float*)d_in[17];

  int N = in_sizes[3];   // 118784
  int E = in_sizes[2];   // 3801088
  int G = N / NPG;       // 1024

  float* ws    = (float*)d_ws;
  float* stats = ws;                       // 256
  float* dinv  = ws + 256;                 // N
  float* h1    = dinv + N;                 // 32N
  float* buf   = h1 + (size_t)N * HID;     // 64N (Wb then h2)
  float* z     = buf + (size_t)G * HPG;    // 32G
  float* out   = (float*)d_out;
  float invN   = 1.0f / (float)N;

  hipMemsetAsync(stats, 0, 256 * sizeof(float), stream);
  k_build<<<G, 1024, 0, stream>>>(ei, ew, dinv, buf, N, E);
  k_conv1<<<G, 1024, 0, stream>>>(x, W1, dinv, buf, h1, stats, N);
  k_conv2<<<G, 1024, 0, stream>>>(h1, W2, g1, be1, stats, dinv, buf,
                                  stats + 64, invN, N);
  k_pool<<<G, 256, 0, stream>>>(buf, g2, be2, stats + 64, Wf1, z, invN, N);
  k_final<<<1, 1024, 0, stream>>>(z, gf, bef, Wf2, bf2, out, G);
}

// Round 17
// 186.660 us; speedup vs baseline: 1.0238x; 1.0238x over previous
//
#include <hip/hip_runtime.h>
#include <hip/hip_cooperative_groups.h>
namespace cg = cooperative_groups;

#define NPG 116          // nodes per graph
#define EPG (NPG * 32)   // 3712 edges per graph
#define HID 32
#define HID2 64
#define EPS 1e-5f
#define AS 136           // bf16 tile k-stride (shorts): 272B, 16B-aligned
#define YSS 40           // ysb/W2T k-stride (shorts): 80B, 16B-aligned
#define NG 4             // graphs per block (256 blocks -> 1 block/CU, safe)

using bf16x8 = __attribute__((ext_vector_type(8))) short;
using f32x4  = __attribute__((ext_vector_type(4))) float;

__device__ __forceinline__ unsigned short f2bf(float f) {
  union { float f; unsigned int i; } cv;
  cv.f = f;
  unsigned int x = cv.i;
  x += 0x7fff + ((x >> 16) & 1);   // RNE
  return (unsigned short)(x >> 16);
}

#define MFMA16(a, b, c) __builtin_amdgcn_mfma_f32_16x16x32_bf16((a), (b), (c), 0, 0, 0)

// ---------------------------------------------------------------------------
// ONE cooperative kernel: 256 blocks x 512 thr -> exactly 1 block/CU, so
// co-residency (required by grid.sync) holds for any VGPR count <= 256.
// Block b owns graphs 4b..4b+3 end-to-end.  W lives in registers as MFMA
// a-frags; h1/h2 live in accumulators across the 3 grid syncs (BN stats).
// ws: stats[256] (s1 q1 | s2 q2 | sf qf), memset 0 per launch.
// ---------------------------------------------------------------------------
__global__ __launch_bounds__(512, 2) void k_fused(
    const float* __restrict__ x, const int* __restrict__ ei,
    const float* __restrict__ ew, const float* __restrict__ W1,
    const float* __restrict__ W2, const float* __restrict__ Wf1,
    const float* __restrict__ Wf2, const float* __restrict__ g1,
    const float* __restrict__ be1, const float* __restrict__ g2,
    const float* __restrict__ be2, const float* __restrict__ gf,
    const float* __restrict__ bef, const float* __restrict__ bf2,
    float* __restrict__ stats, float* __restrict__ out, int N, int E) {
  // region A (53824 B): Wf fp32 during build -> ysb/W2T/L2T during conv2
  __shared__ __align__(16) char regA[NPG * NPG * 4];
  __shared__ __align__(16) short W1T[HID * AS];   // 8704 B
  __shared__ __align__(16) short L1T[HID * AS];   // 8704 B
  __shared__ float dv[NG][NPG];
  __shared__ float ssq[128];       // ss[0..63] qs[64..127]
  __shared__ float cfs[256];       // a1[32] c1[32] a2[64] c2[64] af[32] cf[32]
  __shared__ float emb[NG][128];   // also degs scratch during build
  __shared__ float zloc[NG * 32];
  __shared__ float psum[64];
  __shared__ int   pmaxi[64];

  float* Wf  = (float*)regA;
  short* ysb = (short*)regA;                  // 128*YSS shorts = 10240 B
  short* W2T = (short*)(regA + 10240);        // 64*YSS = 5120 B
  short* L2T = (short*)(regA + 15360);        // 64*AS = 17408 B

  cg::grid_group grid = cg::this_grid();
  const int tid = threadIdx.x;
  const int l = tid & 63, w = tid >> 6;       // 8 waves
  const int rf = l & 15, kg = l >> 4;
  const int rl = w * 16 + rf;                 // this wave's m-tile rows
  const bool rok = rl < NPG;
  const int g0 = NG * blockIdx.x;
  const float invN = 1.0f / (float)N;

  // one-time: zero W1T/L1T (incl. k-pads), stage W1T = W1^T bf16
  for (int i = tid; i < HID * AS / 2; i += 512) {
    ((int*)W1T)[i] = 0;
    ((int*)L1T)[i] = 0;
  }
  __syncthreads();
  for (int i = tid; i < NPG * 8; i += 512) {   // W1 is 116x32, float4 rows
    int k = i >> 3, c4 = (i & 7) * 4;
    float4 v = ((const float4*)W1)[i];
    W1T[(c4 + 0) * AS + k] = (short)f2bf(v.x);
    W1T[(c4 + 1) * AS + k] = (short)f2bf(v.y);
    W1T[(c4 + 2) * AS + k] = (short)f2bf(v.z);
    W1T[(c4 + 3) * AS + k] = (short)f2bf(v.w);
  }

  bf16x8 av[NG][4];     // W a-frags, all graphs, live whole kernel
  f32x4 h1a[NG][2];     // h1 accumulators (cols rf, rf+16)

  // ======== build + conv1, per graph ========
#pragma unroll
  for (int gi = 0; gi < NG; ++gi) {
    const int g = g0 + gi, nb = g * NPG, e0 = g * EPG;
    float* degs = emb[gi];   // scratch (emb not needed until pool)
    for (int i = tid; i < NPG; i += 512) degs[i] = 1.0f;   // self-loop wt
    { float4* p = (float4*)Wf;
      for (int i = tid; i < NPG * 29; i += 512) p[i] = make_float4(0,0,0,0); }
    __syncthreads();
    // edge scan (int4 vectorized) -> deg + raw W atomics
    for (int vi = tid; vi < EPG / 4; vi += 512) {
      int4 s4 = ((const int4*)(ei + e0))[vi];
      int4 d4 = ((const int4*)(ei + E + e0))[vi];
      float4 w4 = ((const float4*)(ew + e0))[vi];
      atomicAdd(&degs[d4.x - nb], w4.x);
      atomicAdd(&Wf[(d4.x - nb) * NPG + (s4.x - nb)], w4.x);
      atomicAdd(&degs[d4.y - nb], w4.y);
      atomicAdd(&Wf[(d4.y - nb) * NPG + (s4.y - nb)], w4.y);
      atomicAdd(&degs[d4.z - nb], w4.z);
      atomicAdd(&Wf[(d4.z - nb) * NPG + (s4.z - nb)], w4.z);
      atomicAdd(&degs[d4.w - nb], w4.w);
      atomicAdd(&Wf[(d4.w - nb) * NPG + (s4.w - nb)], w4.w);
    }
    if (tid < NPG) atomicAdd(&Wf[tid * (NPG + 1)], 1.0f);  // self loops
    __syncthreads();
    if (tid < NPG) dv[gi][tid] = rsqrtf(degs[tid]);

    // av[gi] <- bf16(W rows) from LDS (pads -> 0)
#pragma unroll
    for (int kk = 0; kk < 4; ++kk) {
      int off = kk * 32 + kg * 8;
      bf16x8 a;
#pragma unroll
      for (int j = 0; j < 8; ++j) {
        int c = off + j;
        float v = (rok && c < NPG) ? Wf[rl * NPG + c] : 0.0f;
        a[j] = (short)f2bf(v);
      }
      av[gi][kk] = a;
    }
    // gemm1: acc = x_rows @ W1 (x from global)
    f32x4 a0 = {0.f,0.f,0.f,0.f}, a1v = {0.f,0.f,0.f,0.f};
    {
      const float* xr = x + (size_t)(nb + (rok ? rl : 0)) * NPG;
#pragma unroll
      for (int kk = 0; kk < 4; ++kk) {
        int off = kk * 32 + kg * 8;
        bf16x8 a;
        if (rok && off + 8 <= NPG) {
          float4 v0 = *(const float4*)(xr + off);
          float4 v1 = *(const float4*)(xr + off + 4);
          a[0] = (short)f2bf(v0.x); a[1] = (short)f2bf(v0.y);
          a[2] = (short)f2bf(v0.z); a[3] = (short)f2bf(v0.w);
          a[4] = (short)f2bf(v1.x); a[5] = (short)f2bf(v1.y);
          a[6] = (short)f2bf(v1.z); a[7] = (short)f2bf(v1.w);
        } else {
#pragma unroll
          for (int j = 0; j < 8; ++j) {
            int c = off + j;
            a[j] = (rok && c < NPG) ? (short)f2bf(xr[c]) : (short)0;
          }
        }
        bf16x8 b0 = *(const bf16x8*)&W1T[rf * AS + off];
        bf16x8 b1 = *(const bf16x8*)&W1T[(16 + rf) * AS + off];
        a0 = MFMA16(a, b0, a0);
        a1v = MFMA16(a, b1, a1v);
      }
    }
    __syncthreads();   // dv visible; prior L1T reads done
    // L1T = bf16(dv[row] * lin1)
#pragma unroll
    for (int i = 0; i < 4; ++i) {
      int row = w * 16 + kg * 4 + i;
      if (row < NPG) {
        float dr = dv[gi][row];
        L1T[rf * AS + row] = (short)f2bf(dr * a0[i]);
        L1T[(16 + rf) * AS + row] = (short)f2bf(dr * a1v[i]);
      }
    }
    __syncthreads();   // L1T complete
    // h1acc = W @ L1'
    f32x4 h0 = {0.f,0.f,0.f,0.f}, h1v = {0.f,0.f,0.f,0.f};
#pragma unroll
    for (int kk = 0; kk < 4; ++kk) {
      bf16x8 b0 = *(const bf16x8*)&L1T[rf * AS + kk * 32 + kg * 8];
      bf16x8 b1 = *(const bf16x8*)&L1T[(16 + rf) * AS + kk * 32 + kg * 8];
      h0 = MFMA16(av[gi][kk], b0, h0);
      h1v = MFMA16(av[gi][kk], b1, h1v);
    }
    h1a[gi][0] = h0;
    h1a[gi][1] = h1v;
    __syncthreads();   // L1T/Wf reusable
  }

  // conv2 LDS prep (Wf dead): zero ysb + L2T (incl pads), stage W2T
  for (int i = tid; i < 2560; i += 512) ((int*)regA)[i] = 0;           // ysb
  for (int i = tid; i < 4352; i += 512) ((int*)(regA + 15360))[i] = 0; // L2T
  if (tid < 512) {
    int k = tid >> 4, c4 = (tid & 15) * 4;   // W2 is 32x64, 512 float4
    float4 v = ((const float4*)W2)[tid];
    W2T[(c4 + 0) * YSS + k] = (short)f2bf(v.x);
    W2T[(c4 + 1) * YSS + k] = (short)f2bf(v.y);
    W2T[(c4 + 2) * YSS + k] = (short)f2bf(v.z);
    W2T[(c4 + 3) * YSS + k] = (short)f2bf(v.w);
  }
  if (tid < 64) { ssq[tid] = 0.f; ssq[64 + tid] = 0.f; }
  __syncthreads();
  // stats1 partials
  {
    float s0 = 0.f, q0 = 0.f, s1 = 0.f, q1 = 0.f;
#pragma unroll
    for (int gi = 0; gi < NG; ++gi)
#pragma unroll
      for (int i = 0; i < 4; ++i) {
        int row = w * 16 + kg * 4 + i;
        if (row < NPG) {
          float dr = dv[gi][row];
          float v0 = dr * h1a[gi][0][i], v1 = dr * h1a[gi][1][i];
          s0 += v0; q0 += v0 * v0;
          s1 += v1; q1 += v1 * v1;
        }
      }
    atomicAdd(&ssq[rf], s0);      atomicAdd(&ssq[64 + rf], q0);
    atomicAdd(&ssq[16 + rf], s1); atomicAdd(&ssq[80 + rf], q1);
  }
  __syncthreads();
  if (tid < HID) {
    atomicAdd(&stats[tid], ssq[tid]);
    atomicAdd(&stats[32 + tid], ssq[64 + tid]);
  }
  grid.sync();   // ======== BN1 stats global ========

  if (tid < HID) {
    float m = stats[tid] * invN;
    float v = stats[32 + tid] * invN - m * m;
    float a = g1[tid] * rsqrtf(v + EPS);
    cfs[tid] = a;
    cfs[32 + tid] = be1[tid] - m * a;
  }
  if (tid < 64) { ssq[tid] = 0.f; ssq[64 + tid] = 0.f; }
  __syncthreads();

  f32x4 h2a[NG][4];
#pragma unroll
  for (int gi = 0; gi < NG; ++gi) {
    // ysb = bf16(dv * relu(a1*h1 + c1))
#pragma unroll
    for (int i = 0; i < 4; ++i) {
      int row = w * 16 + kg * 4 + i;
      if (row < NPG) {
        float dr = dv[gi][row];
        float hv0 = dr * h1a[gi][0][i], hv1 = dr * h1a[gi][1][i];
        float y0 = dr * fmaxf(0.f, cfs[rf] * hv0 + cfs[32 + rf]);
        float y1 = dr * fmaxf(0.f, cfs[16 + rf] * hv1 + cfs[48 + rf]);
        ysb[row * YSS + rf] = (short)f2bf(y0);
        ysb[row * YSS + 16 + rf] = (short)f2bf(y1);
      }
    }
    __syncthreads();
    // gemm2: L2T = ys' @ W2 (32 tiles / 8 waves)
#pragma unroll
    for (int u = 0; u < 4; ++u) {
      int t = w + 8 * u;
      int mt2 = t >> 2, nt = t & 3;
      bf16x8 a = *(const bf16x8*)&ysb[(mt2 * 16 + rf) * YSS + kg * 8];
      bf16x8 bb = *(const bf16x8*)&W2T[(nt * 16 + rf) * YSS + kg * 8];
      f32x4 acc = {0.f, 0.f, 0.f, 0.f};
      acc = MFMA16(a, bb, acc);
      int col = nt * 16 + rf;
#pragma unroll
      for (int i = 0; i < 4; ++i) {
        int row = mt2 * 16 + kg * 4 + i;
        if (row < NPG) L2T[col * AS + row] = (short)f2bf(acc[i]);
      }
    }
    __syncthreads();
    // h2acc = W @ L2'
#pragma unroll
    for (int nt = 0; nt < 4; ++nt) h2a[gi][nt] = (f32x4){0.f,0.f,0.f,0.f};
#pragma unroll
    for (int kk = 0; kk < 4; ++kk) {
#pragma unroll
      for (int nt = 0; nt < 4; ++nt) {
        bf16x8 bb = *(const bf16x8*)&L2T[(nt * 16 + rf) * AS + kk * 32 + kg * 8];
        h2a[gi][nt] = MFMA16(av[gi][kk], bb, h2a[gi][nt]);
      }
    }
    __syncthreads();   // before ysb/L2T rewrite for next graph
  }
  // stats2 partials
#pragma unroll
  for (int nt = 0; nt < 4; ++nt) {
    float s_ = 0.f, q_ = 0.f;
#pragma unroll
    for (int gi = 0; gi < NG; ++gi)
#pragma unroll
      for (int i = 0; i < 4; ++i) {
        int row = w * 16 + kg * 4 + i;
        if (row < NPG) {
          float v = dv[gi][row] * h2a[gi][nt][i];
          s_ += v; q_ += v * v;
        }
      }
    atomicAdd(&ssq[nt * 16 + rf], s_);
    atomicAdd(&ssq[64 + nt * 16 + rf], q_);
  }
  __syncthreads();
  if (tid < HID2) {
    atomicAdd(&stats[64 + tid], ssq[tid]);
    atomicAdd(&stats[128 + tid], ssq[64 + tid]);
  }
  grid.sync();   // ======== BN2 stats global ========

  if (tid < HID2) {
    float m = stats[64 + tid] * invN;
    float v = stats[128 + tid] * invN - m * m;
    float a = g2[tid] * rsqrtf(v + EPS);
    cfs[64 + tid] = a;
    cfs[128 + tid] = be2[tid] - m * a;
  }
  __syncthreads();
  // pool per graph: mean/max of relu(BN2(h2)) over rows
#pragma unroll
  for (int gi = 0; gi < NG; ++gi) {
    if (tid < 64) { psum[tid] = 0.f; pmaxi[tid] = 0; }
    __syncthreads();
#pragma unroll
    for (int nt = 0; nt < 4; ++nt) {
      int col = nt * 16 + rf;
      float a2 = cfs[64 + col], c2 = cfs[128 + col];
      float s_ = 0.f, mx = 0.f;
#pragma unroll
      for (int i = 0; i < 4; ++i) {
        int row = w * 16 + kg * 4 + i;
        if (row < NPG) {
          float hv = dv[gi][row] * h2a[gi][nt][i];
          float y = fmaxf(0.f, a2 * hv + c2);
          s_ += y; mx = fmaxf(mx, y);
        }
      }
      atomicAdd(&psum[col], s_);
      atomicMax(&pmaxi[col], __float_as_int(mx));   // y >= 0
    }
    __syncthreads();
    if (tid < 64) {
      emb[gi][tid] = psum[tid] * (1.0f / NPG);
      emb[gi][64 + tid] = __int_as_float(pmaxi[tid]);
    }
    __syncthreads();
  }
  // FC1 -> zloc, BNf stat partials
  if (tid < NG * 32) {
    int gi = tid >> 5, c = tid & 31;
    float acc = 0.f;
#pragma unroll
    for (int k = 0; k < 128; ++k) acc += emb[gi][k] * Wf1[k * 32 + c];
    zloc[tid] = acc;
  }
  __syncthreads();
  if (tid < 32) {
    float s_ = 0.f, q_ = 0.f;
#pragma unroll
    for (int gi = 0; gi < NG; ++gi) {
      float zv = zloc[gi * 32 + tid];
      s_ += zv; q_ += zv * zv;
    }
    atomicAdd(&stats[192 + tid], s_);
    atomicAdd(&stats[224 + tid], q_);
  }
  grid.sync();   // ======== BNf stats global ========

  if (tid < 32) {
    float iG = 1.0f / (float)(NG * gridDim.x);
    float m = stats[192 + tid] * iG;
    float v = stats[224 + tid] * iG - m * m;
    float a = gf[tid] * rsqrtf(v + EPS);
    cfs[192 + tid] = a;
    cfs[224 + tid] = bef[tid] - m * a;
  }
  __syncthreads();
  if (tid < NG) {
    float o0 = bf2[0], o1 = bf2[1];
#pragma unroll
    for (int j = 0; j < 32; ++j) {
      float y = fmaxf(0.f, cfs[192 + j] * zloc[tid * 32 + j] + cfs[224 + j]);
      o0 += y * Wf2[2 * j];
      o1 += y * Wf2[2 * j + 1];
    }
    out[(g0 + tid) * 2] = o0;
    out[(g0 + tid) * 2 + 1] = o1;
  }
}

extern "C" void kernel_launch(void* const* d_in, const int* in_sizes, int n_in,
                              void* d_out, int out_size, void* d_ws, size_t ws_size,
                              hipStream_t stream) {
  const float* x   = (const float*)d_in[0];
  const int*   ei  = (const int*)d_in[1];
  const float* ew  = (const float*)d_in[2];
  // d_in[3]=batch (implicit), d_in[5]=b1, d_in[9]=b2, d_in[13]=bf1 cancel
  // under training-mode BN and are unused.
  const float* W1  = (const float*)d_in[4];
  const float* g1  = (const float*)d_in[6];
  const float* be1 = (const float*)d_in[7];
  const float* W2  = (const float*)d_in[8];
  const float* g2  = (const float*)d_in[10];
  const float* be2 = (const float*)d_in[11];
  const float* Wf1 = (const float*)d_in[12];
  const float* gf  = (const float*)d_in[14];
  const float* bef = (const float*)d_in[15];
  const float* Wf2 = (const float*)d_in[16];
  const float* bf2 = (const float*)d_in[17];

  int N = in_sizes[3];   // 118784
  int E = in_sizes[2];   // 3801088
  int G = N / NPG;       // 1024

  float* stats = (float*)d_ws;     // 256 floats
  float* out   = (float*)d_out;

  hipMemsetAsync(stats, 0, 256 * sizeof(float), stream);

  void* args[] = {&x, &ei, &ew, &W1, &W2, &Wf1, &Wf2, &g1, &be1, &g2, &be2,
                  &gf, &bef, &bf2, &stats, &out, &N, &E};
  hipLaunchCooperativeKernel((void*)k_fused, dim3(G / NG), dim3(512), args, 0,
                             stream);
}